// Round 7
// baseline (1862.040 us; speedup 1.0000x reference)
//
#include <hip/hip_runtime.h>
#include <hip/hip_bf16.h>
#include <stdint.h>

#define NS   200000
#define ND   100000
#define NTOT 300000
#define NE   1600000
#define DINK 128
#define NH   8
#define DH   16
#define HD   128
#define NAUG 144
#define NEG  0.2f

#define NBUK   1024
#define SSHIFT 8          // src >> 8  -> src bucket (782 used)
#define DSHIFT 7          // dst >> 7  -> dst bucket (782 used), 128 dst per bucket
#define EPB    8192       // edges per partition block
#define NPB    196        // ceil(NE / EPB)
#define NDB    782        // ceil(ND / 128) dst buckets / agg blocks

typedef __attribute__((ext_vector_type(8))) short short8;
typedef __attribute__((ext_vector_type(4))) float f32x4;

__device__ inline uint32_t bf16rne(uint32_t u) {
  return (u + 0x7fffu + ((u >> 16) & 1u)) >> 16;
}
__device__ inline uint32_t pack_bf2(float a, float b) {
  union { float f; uint32_t u; } ua, ub; ua.f = a; ub.f = b;
  return (bf16rne(ua.u) & 0xffffu) | (bf16rne(ub.u) << 16);
}

// Build augmented weight [128][144] = [W | W@attn_l | W@attn_r]
__global__ void k_build_waug(const float* __restrict__ W, const float* __restrict__ al,
                             const float* __restrict__ ar, float* __restrict__ Waug) {
  int idx = blockIdx.x * blockDim.x + threadIdx.x;
  if (idx >= DINK * NAUG) return;
  int k = idx / NAUG, c = idx % NAUG;
  float v;
  if (c < HD) {
    v = W[k * HD + c];
  } else {
    int hh = (c - HD) & 7;
    const float* a = (c < HD + NH) ? al : ar;
    float s = 0.f;
    for (int d = 0; d < DH; ++d) s += W[k * HD + hh * DH + d] * a[hh * DH + d];
    v = s;
  }
  Waug[k * NAUG + c] = v;
}

// MFMA bf16 GEMM: [300k x 128] @ [128 x 144] -> h (bf16) + el/er (f32)
__global__ __launch_bounds__(256) void k_gemm_mfma(
    const float* __restrict__ fs, const float* __restrict__ fd,
    const float* __restrict__ Waug, __hip_bfloat16* __restrict__ hbf,
    float* __restrict__ el, float* __restrict__ er) {
  __shared__ short lds_w[NAUG * DINK];
  __shared__ short lds_a[64 * DINK];
  int tid = threadIdx.x;
  int m0 = blockIdx.x * 64;

  for (int idx = tid; idx < NAUG * DINK; idx += 256) {
    int k = idx / NAUG, n = idx - k * NAUG;
    union { float f; uint32_t u; } uv; uv.f = Waug[idx];
    uint32_t off = ((uint32_t)(n * DINK + k) * 2u) ^ ((uint32_t)(n & 7) << 4);
    *(short*)((char*)lds_w + off) = (short)bf16rne(uv.u);
  }
  {
    int row = tid >> 2;
    int grow = m0 + row;
    int cbase = (tid & 3) * 32;
    bool valid = grow < NTOT;
    const float* base = valid ? ((grow < NS) ? (fs + (size_t)grow * DINK)
                                             : (fd + (size_t)(grow - NS) * DINK)) : (const float*)0;
#pragma unroll
    for (int c = 0; c < 4; ++c) {
      float4 v0 = valid ? *(const float4*)(base + cbase + c * 8)     : make_float4(0,0,0,0);
      float4 v1 = valid ? *(const float4*)(base + cbase + c * 8 + 4) : make_float4(0,0,0,0);
      uint4 p;
      p.x = pack_bf2(v0.x, v0.y); p.y = pack_bf2(v0.z, v0.w);
      p.z = pack_bf2(v1.x, v1.y); p.w = pack_bf2(v1.z, v1.w);
      uint32_t off = ((uint32_t)(row * DINK + cbase + c * 8) * 2u) ^ ((uint32_t)(row & 7) << 4);
      *(uint4*)((char*)lds_a + off) = p;
    }
  }
  __syncthreads();

  int wid = tid >> 6, lane = tid & 63;
  int lr = lane & 15, lg = lane >> 4;
  short8 af[4];
#pragma unroll
  for (int s = 0; s < 4; ++s) {
    uint32_t off = ((uint32_t)((wid * 16 + lr) * DINK + s * 32 + lg * 8) * 2u)
                 ^ ((uint32_t)(lr & 7) << 4);
    af[s] = *(short8*)((char*)lds_a + off);
  }
  int orow0 = m0 + wid * 16 + lg * 4;
#pragma unroll
  for (int t = 0; t < 9; ++t) {
    f32x4 acc = {0.f, 0.f, 0.f, 0.f};
#pragma unroll
    for (int s = 0; s < 4; ++s) {
      uint32_t off = ((uint32_t)((t * 16 + lr) * DINK + s * 32 + lg * 8) * 2u)
                   ^ ((uint32_t)(lr & 7) << 4);
      short8 bfr = *(short8*)((char*)lds_w + off);
      acc = __builtin_amdgcn_mfma_f32_16x16x32_bf16(af[s], bfr, acc, 0, 0, 0);
    }
#pragma unroll
    for (int j = 0; j < 4; ++j) {
      int row = orow0 + j;
      if (row >= NTOT) continue;
      float v = acc[j];
      if (t < 8)          hbf[(size_t)row * HD + t * 16 + lr] = __float2bfloat16(v);
      else if (lr < 8)    el[(size_t)row * NH + lr] = v;
      else                er[(size_t)row * NH + (lr - 8)] = v;
    }
  }
}

// One pass: src-bucket + dst-bucket histograms (both LDS-binned)
__global__ __launch_bounds__(256) void k_hist2(
    const int* __restrict__ esrc, const int* __restrict__ edst,
    int* __restrict__ sbh, int* __restrict__ dbh) {
  __shared__ int ls[NBUK];
  __shared__ int ld[NBUK];
  int tid = threadIdx.x;
  for (int i = tid; i < NBUK; i += 256) { ls[i] = 0; ld[i] = 0; }
  __syncthreads();
  for (int e = blockIdx.x * 256 + tid; e < NE; e += gridDim.x * 256) {
    atomicAdd(&ls[esrc[e] >> SSHIFT], 1);
    atomicAdd(&ld[edst[e] >> DSHIFT], 1);
  }
  __syncthreads();
  for (int i = tid; i < NBUK; i += 256) {
    if (ls[i]) atomicAdd(&sbh[i], ls[i]);
    if (ld[i]) atomicAdd(&dbh[i], ld[i]);
  }
}

// Exclusive scan of 1024 bucket counts -> offs and cur
__global__ void k_scan_buckets(const int* __restrict__ bh, int* __restrict__ offs,
                               int* __restrict__ cur) {
  __shared__ int sd[NBUK];
  int t = threadIdx.x;
  int v = bh[t];
  sd[t] = v;
  __syncthreads();
  for (int s = 1; s < NBUK; s <<= 1) {
    int a = (t >= s) ? sd[t - s] : 0;
    __syncthreads();
    sd[t] += a;
    __syncthreads();
  }
  int ex = sd[t] - v;
  offs[t] = ex;
  cur[t] = ex;
}

// Pass 1: partition raw edges by src-bucket -> part1 (src-bucket-major)
__global__ __launch_bounds__(256) void k_partition1(
    const int* __restrict__ esrc, const int* __restrict__ edst,
    int* __restrict__ scur, int2* __restrict__ part1) {
  __shared__ int lcnt[NBUK];
  __shared__ int lbase[NBUK];
  int tid = threadIdx.x;
  int e0 = blockIdx.x * EPB;
  for (int i = tid; i < NBUK; i += 256) lcnt[i] = 0;
  __syncthreads();
#pragma unroll
  for (int i = 0; i < EPB / 256; ++i) {
    int e = e0 + i * 256 + tid;
    if (e < NE) atomicAdd(&lcnt[esrc[e] >> SSHIFT], 1);
  }
  __syncthreads();
  for (int i = tid; i < NBUK; i += 256) {
    int c = lcnt[i];
    lbase[i] = c ? atomicAdd(&scur[i], c) : 0;
  }
  __syncthreads();
#pragma unroll
  for (int i = 0; i < EPB / 256; ++i) {
    int e = e0 + i * 256 + tid;
    if (e < NE) {
      int s = esrc[e];
      int d = edst[e];
      int slot = atomicAdd(&lbase[s >> SSHIFT], 1);
      part1[slot] = make_int2(s, d);
    }
  }
}

// Pass 2: partition part1 by dst-bucket -> part2 (dst-bucket-major, src-ascending-ish)
__global__ __launch_bounds__(256) void k_partition2(
    const int2* __restrict__ part1, int* __restrict__ dcur, int2* __restrict__ part2) {
  __shared__ int lcnt[NBUK];
  __shared__ int lbase[NBUK];
  int tid = threadIdx.x;
  int e0 = blockIdx.x * EPB;
  for (int i = tid; i < NBUK; i += 256) lcnt[i] = 0;
  __syncthreads();
#pragma unroll
  for (int i = 0; i < EPB / 256; ++i) {
    int e = e0 + i * 256 + tid;
    if (e < NE) atomicAdd(&lcnt[part1[e].y >> DSHIFT], 1);
  }
  __syncthreads();
  for (int i = tid; i < NBUK; i += 256) {
    int c = lcnt[i];
    lbase[i] = c ? atomicAdd(&dcur[i], c) : 0;
  }
  __syncthreads();
#pragma unroll
  for (int i = 0; i < EPB / 256; ++i) {
    int e = e0 + i * 256 + tid;
    if (e < NE) {
      int2 p = part1[e];
      int slot = atomicAdd(&lbase[p.y >> DSHIFT], 1);
      part2[slot] = p;
    }
  }
}

// One block per dst-bucket (128 dst): LDS f32 accumulators, edge-parallel ds atomics,
// then normalize + bias + sequential out write.
__global__ __launch_bounds__(256) void k_agg_bucket(
    const int2* __restrict__ part2, const int* __restrict__ dboffs,
    const float* __restrict__ el, const float* __restrict__ er,
    const uint32_t* __restrict__ h2, const float* __restrict__ bias,
    float* __restrict__ out) {
  __shared__ float acc[128 * 130];   // [dloc][ch], stride 130 to de-align
  __shared__ float zz[128 * 8];      // [dloc][head]
  __shared__ float erl[128 * 8];     // er of the 128 dst
  int tid = threadIdx.x;
  int b = blockIdx.x;
  int d0 = b << DSHIFT;
  int ndst = ND - d0; if (ndst > 128) ndst = 128;

  for (int i = tid; i < 128 * 130; i += 256) acc[i] = 0.f;
  for (int i = tid; i < 128 * 8; i += 256) zz[i] = 0.f;
  for (int i = tid; i < ndst * 8; i += 256) erl[i] = er[(size_t)(NS + d0) * 8 + i];
  __syncthreads();

  int wv = tid >> 6, lane = tid & 63;
  int hh = lane >> 3;
  int c2 = lane << 1;

  // self loops
  for (int dl = wv; dl < ndst; dl += 4) {
    int g = NS + d0 + dl;
    float w0 = el[(size_t)g * 8 + hh] + erl[dl * 8 + hh];
    w0 = (w0 < 0.f) ? NEG * w0 : w0;
    w0 = __expf(w0);
    uint32_t hv = h2[(size_t)g * 64 + lane];
    atomicAdd(&acc[dl * 130 + c2],     w0 * __uint_as_float(hv << 16));
    atomicAdd(&acc[dl * 130 + c2 + 1], w0 * __uint_as_float(hv & 0xffff0000u));
    if ((lane & 7) == 0) atomicAdd(&zz[dl * 8 + hh], w0);
  }

  // edges: each wave takes a contiguous quarter (preserves ascending src order)
  int s0 = dboffs[b], s1 = dboffs[b + 1];
  int len = s1 - s0;
  int e  = s0 + (int)(((long long)len * wv) >> 2);
  int ee = s0 + (int)(((long long)len * (wv + 1)) >> 2);
  for (; e + 4 <= ee; e += 4) {
    int2 p0 = part2[e], p1 = part2[e + 1], p2 = part2[e + 2], p3 = part2[e + 3];
    uint32_t hb0 = h2[(size_t)p0.x * 64 + lane];
    uint32_t hb1 = h2[(size_t)p1.x * 64 + lane];
    uint32_t hb2 = h2[(size_t)p2.x * 64 + lane];
    uint32_t hb3 = h2[(size_t)p3.x * 64 + lane];
    float a0 = el[(size_t)p0.x * 8 + hh];
    float a1 = el[(size_t)p1.x * 8 + hh];
    float a2 = el[(size_t)p2.x * 8 + hh];
    float a3 = el[(size_t)p3.x * 8 + hh];
    int dl; float w;
    dl = p0.y - d0; w = a0 + erl[dl * 8 + hh]; w = (w < 0.f) ? NEG * w : w; w = __expf(w);
    atomicAdd(&acc[dl * 130 + c2],     w * __uint_as_float(hb0 << 16));
    atomicAdd(&acc[dl * 130 + c2 + 1], w * __uint_as_float(hb0 & 0xffff0000u));
    if ((lane & 7) == 0) atomicAdd(&zz[dl * 8 + hh], w);
    dl = p1.y - d0; w = a1 + erl[dl * 8 + hh]; w = (w < 0.f) ? NEG * w : w; w = __expf(w);
    atomicAdd(&acc[dl * 130 + c2],     w * __uint_as_float(hb1 << 16));
    atomicAdd(&acc[dl * 130 + c2 + 1], w * __uint_as_float(hb1 & 0xffff0000u));
    if ((lane & 7) == 0) atomicAdd(&zz[dl * 8 + hh], w);
    dl = p2.y - d0; w = a2 + erl[dl * 8 + hh]; w = (w < 0.f) ? NEG * w : w; w = __expf(w);
    atomicAdd(&acc[dl * 130 + c2],     w * __uint_as_float(hb2 << 16));
    atomicAdd(&acc[dl * 130 + c2 + 1], w * __uint_as_float(hb2 & 0xffff0000u));
    if ((lane & 7) == 0) atomicAdd(&zz[dl * 8 + hh], w);
    dl = p3.y - d0; w = a3 + erl[dl * 8 + hh]; w = (w < 0.f) ? NEG * w : w; w = __expf(w);
    atomicAdd(&acc[dl * 130 + c2],     w * __uint_as_float(hb3 << 16));
    atomicAdd(&acc[dl * 130 + c2 + 1], w * __uint_as_float(hb3 & 0xffff0000u));
    if ((lane & 7) == 0) atomicAdd(&zz[dl * 8 + hh], w);
  }
  for (; e < ee; ++e) {
    int2 p = part2[e];
    uint32_t hb = h2[(size_t)p.x * 64 + lane];
    float a = el[(size_t)p.x * 8 + hh];
    int dl = p.y - d0;
    float w = a + erl[dl * 8 + hh];
    w = (w < 0.f) ? NEG * w : w; w = __expf(w);
    atomicAdd(&acc[dl * 130 + c2],     w * __uint_as_float(hb << 16));
    atomicAdd(&acc[dl * 130 + c2 + 1], w * __uint_as_float(hb & 0xffff0000u));
    if ((lane & 7) == 0) atomicAdd(&zz[dl * 8 + hh], w);
  }
  __syncthreads();

  // normalize + bias + write
  float b0 = bias[c2], b1 = bias[c2 + 1];
  for (int dl = wv; dl < ndst; dl += 4) {
    float inv = 1.f / zz[dl * 8 + hh];
    float2 o;
    o.x = acc[dl * 130 + c2]     * inv + b0;
    o.y = acc[dl * 130 + c2 + 1] * inv + b1;
    *(float2*)&out[(size_t)(d0 + dl) * HD + c2] = o;
  }
}

extern "C" void kernel_launch(void* const* d_in, const int* in_sizes, int n_in,
                              void* d_out, int out_size, void* d_ws, size_t ws_size,
                              hipStream_t stream) {
  const float* fs   = (const float*)d_in[0];
  const float* fd   = (const float*)d_in[1];
  const float* W    = (const float*)d_in[2];
  const float* al   = (const float*)d_in[3];
  const float* ar   = (const float*)d_in[4];
  const float* bias = (const float*)d_in[5];
  const int* esrc   = (const int*)d_in[6];
  const int* edst   = (const int*)d_in[7];
  float* out = (float*)d_out;
  (void)in_sizes; (void)n_in; (void)out_size; (void)ws_size;

  char* ws = (char*)d_ws;
  size_t o = 0;
  auto alloc = [&](size_t b) { size_t r = o; o += (b + 255) & ~(size_t)255; return r; };
  float*  Waug   = (float*)(ws + alloc((size_t)DINK * NAUG * 4));
  __hip_bfloat16* hbf = (__hip_bfloat16*)(ws + alloc((size_t)NTOT * HD * 2));
  float*  el     = (float*)(ws + alloc((size_t)NTOT * NH * 4));
  float*  er     = (float*)(ws + alloc((size_t)NTOT * NH * 4));
  int*    sbh    = (int*)(ws + alloc((size_t)NBUK * 4));
  int*    sboffs = (int*)(ws + alloc((size_t)NBUK * 4));
  int*    scur   = (int*)(ws + alloc((size_t)NBUK * 4));
  int*    dbh    = (int*)(ws + alloc((size_t)NBUK * 4));
  int*    dboffs = (int*)(ws + alloc((size_t)NBUK * 4));
  int*    dcur   = (int*)(ws + alloc((size_t)NBUK * 4));
  int2*   part1  = (int2*)(ws + alloc((size_t)NE * 8));
  int2*   part2  = (int2*)(ws + alloc((size_t)NE * 8));

  hipMemsetAsync(sbh, 0, (size_t)NBUK * 4, stream);
  hipMemsetAsync(dbh, 0, (size_t)NBUK * 4, stream);
  k_build_waug<<<(DINK * NAUG + 255) / 256, 256, 0, stream>>>(W, al, ar, Waug);
  k_hist2<<<256, 256, 0, stream>>>(esrc, edst, sbh, dbh);
  k_gemm_mfma<<<(NTOT + 63) / 64, 256, 0, stream>>>(fs, fd, Waug, hbf, el, er);
  k_scan_buckets<<<1, NBUK, 0, stream>>>(sbh, sboffs, scur);
  k_scan_buckets<<<1, NBUK, 0, stream>>>(dbh, dboffs, dcur);
  k_partition1<<<NPB, 256, 0, stream>>>(esrc, edst, scur, part1);
  k_partition2<<<NPB, 256, 0, stream>>>(part1, dcur, part2);
  k_agg_bucket<<<NDB, 256, 0, stream>>>(part2, dboffs, el, er, (const uint32_t*)hbf, bias, out);
}

// Round 11
// 459.045 us; speedup vs baseline: 4.0563x; 4.0563x over previous
//
#include <hip/hip_runtime.h>
#include <hip/hip_bf16.h>
#include <stdint.h>

#define NS   200000
#define ND   100000
#define NTOT 300000
#define NE   1600000
#define DINK 128
#define NH   8
#define DH   16
#define HD   128
#define NAUG 144
#define NEG  0.2f

#define NBUK   1024
#define SSHIFT 8          // src >> 8  -> src bucket
#define DSHIFT 7          // dst >> 7  -> dst bucket, 128 dst per bucket
#define EPB    8192       // edges per partition block
#define NPB    196        // ceil(NE / EPB)
#define NDB    782        // ceil(ND / 128) dst buckets

typedef __attribute__((ext_vector_type(8))) short short8;
typedef __attribute__((ext_vector_type(4))) float f32x4;

__device__ inline uint32_t bf16rne(uint32_t u) {
  return (u + 0x7fffu + ((u >> 16) & 1u)) >> 16;
}
__device__ inline uint32_t pack_bf2(float a, float b) {
  union { float f; uint32_t u; } ua, ub; ua.f = a; ub.f = b;
  return (bf16rne(ua.u) & 0xffffu) | (bf16rne(ub.u) << 16);
}

// Build augmented weight [128][144] = [W | W@attn_l | W@attn_r]
__global__ void k_build_waug(const float* __restrict__ W, const float* __restrict__ al,
                             const float* __restrict__ ar, float* __restrict__ Waug) {
  int idx = blockIdx.x * blockDim.x + threadIdx.x;
  if (idx >= DINK * NAUG) return;
  int k = idx / NAUG, c = idx % NAUG;
  float v;
  if (c < HD) {
    v = W[k * HD + c];
  } else {
    int hh = (c - HD) & 7;
    const float* a = (c < HD + NH) ? al : ar;
    float s = 0.f;
    for (int d = 0; d < DH; ++d) s += W[k * HD + hh * DH + d] * a[hh * DH + d];
    v = s;
  }
  Waug[k * NAUG + c] = v;
}

// MFMA bf16 GEMM: [300k x 128] @ [128 x 144] -> h (bf16) + el/er (f32)
__global__ __launch_bounds__(256) void k_gemm_mfma(
    const float* __restrict__ fs, const float* __restrict__ fd,
    const float* __restrict__ Waug, __hip_bfloat16* __restrict__ hbf,
    float* __restrict__ el, float* __restrict__ er) {
  __shared__ short lds_w[NAUG * DINK];
  __shared__ short lds_a[64 * DINK];
  int tid = threadIdx.x;
  int m0 = blockIdx.x * 64;

  for (int idx = tid; idx < NAUG * DINK; idx += 256) {
    int k = idx / NAUG, n = idx - k * NAUG;
    union { float f; uint32_t u; } uv; uv.f = Waug[idx];
    uint32_t off = ((uint32_t)(n * DINK + k) * 2u) ^ ((uint32_t)(n & 7) << 4);
    *(short*)((char*)lds_w + off) = (short)bf16rne(uv.u);
  }
  {
    int row = tid >> 2;
    int grow = m0 + row;
    int cbase = (tid & 3) * 32;
    bool valid = grow < NTOT;
    const float* base = valid ? ((grow < NS) ? (fs + (size_t)grow * DINK)
                                             : (fd + (size_t)(grow - NS) * DINK)) : (const float*)0;
#pragma unroll
    for (int c = 0; c < 4; ++c) {
      float4 v0 = valid ? *(const float4*)(base + cbase + c * 8)     : make_float4(0,0,0,0);
      float4 v1 = valid ? *(const float4*)(base + cbase + c * 8 + 4) : make_float4(0,0,0,0);
      uint4 p;
      p.x = pack_bf2(v0.x, v0.y); p.y = pack_bf2(v0.z, v0.w);
      p.z = pack_bf2(v1.x, v1.y); p.w = pack_bf2(v1.z, v1.w);
      uint32_t off = ((uint32_t)(row * DINK + cbase + c * 8) * 2u) ^ ((uint32_t)(row & 7) << 4);
      *(uint4*)((char*)lds_a + off) = p;
    }
  }
  __syncthreads();

  int wid = tid >> 6, lane = tid & 63;
  int lr = lane & 15, lg = lane >> 4;
  short8 af[4];
#pragma unroll
  for (int s = 0; s < 4; ++s) {
    uint32_t off = ((uint32_t)((wid * 16 + lr) * DINK + s * 32 + lg * 8) * 2u)
                 ^ ((uint32_t)(lr & 7) << 4);
    af[s] = *(short8*)((char*)lds_a + off);
  }
  int orow0 = m0 + wid * 16 + lg * 4;
#pragma unroll
  for (int t = 0; t < 9; ++t) {
    f32x4 acc = {0.f, 0.f, 0.f, 0.f};
#pragma unroll
    for (int s = 0; s < 4; ++s) {
      uint32_t off = ((uint32_t)((t * 16 + lr) * DINK + s * 32 + lg * 8) * 2u)
                   ^ ((uint32_t)(lr & 7) << 4);
      short8 bfr = *(short8*)((char*)lds_w + off);
      acc = __builtin_amdgcn_mfma_f32_16x16x32_bf16(af[s], bfr, acc, 0, 0, 0);
    }
#pragma unroll
    for (int j = 0; j < 4; ++j) {
      int row = orow0 + j;
      if (row >= NTOT) continue;
      float v = acc[j];
      if (t < 8)          hbf[(size_t)row * HD + t * 16 + lr] = __float2bfloat16(v);
      else if (lr < 8)    el[(size_t)row * NH + lr] = v;
      else                er[(size_t)row * NH + (lr - 8)] = v;
    }
  }
}

// One pass: src-bucket + dst-bucket histograms (both LDS-binned)
__global__ __launch_bounds__(256) void k_hist2(
    const int* __restrict__ esrc, const int* __restrict__ edst,
    int* __restrict__ sbh, int* __restrict__ dbh) {
  __shared__ int ls[NBUK];
  __shared__ int ld[NBUK];
  int tid = threadIdx.x;
  for (int i = tid; i < NBUK; i += 256) { ls[i] = 0; ld[i] = 0; }
  __syncthreads();
  for (int e = blockIdx.x * 256 + tid; e < NE; e += gridDim.x * 256) {
    atomicAdd(&ls[esrc[e] >> SSHIFT], 1);
    atomicAdd(&ld[edst[e] >> DSHIFT], 1);
  }
  __syncthreads();
  for (int i = tid; i < NBUK; i += 256) {
    if (ls[i]) atomicAdd(&sbh[i], ls[i]);
    if (ld[i]) atomicAdd(&dbh[i], ld[i]);
  }
}

// Exclusive scan of 1024 bucket counts -> offs and cur
__global__ void k_scan_buckets(const int* __restrict__ bh, int* __restrict__ offs,
                               int* __restrict__ cur) {
  __shared__ int sd[NBUK];
  int t = threadIdx.x;
  int v = bh[t];
  sd[t] = v;
  __syncthreads();
  for (int s = 1; s < NBUK; s <<= 1) {
    int a = (t >= s) ? sd[t - s] : 0;
    __syncthreads();
    sd[t] += a;
    __syncthreads();
  }
  int ex = sd[t] - v;
  offs[t] = ex;
  cur[t] = ex;
}

// Pass 1: partition raw edges by src-bucket -> part1 (src-bucket-major)
__global__ __launch_bounds__(256) void k_partition1(
    const int* __restrict__ esrc, const int* __restrict__ edst,
    int* __restrict__ scur, int2* __restrict__ part1) {
  __shared__ int lcnt[NBUK];
  __shared__ int lbase[NBUK];
  int tid = threadIdx.x;
  int e0 = blockIdx.x * EPB;
  for (int i = tid; i < NBUK; i += 256) lcnt[i] = 0;
  __syncthreads();
#pragma unroll
  for (int i = 0; i < EPB / 256; ++i) {
    int e = e0 + i * 256 + tid;
    if (e < NE) atomicAdd(&lcnt[esrc[e] >> SSHIFT], 1);
  }
  __syncthreads();
  for (int i = tid; i < NBUK; i += 256) {
    int c = lcnt[i];
    lbase[i] = c ? atomicAdd(&scur[i], c) : 0;
  }
  __syncthreads();
#pragma unroll
  for (int i = 0; i < EPB / 256; ++i) {
    int e = e0 + i * 256 + tid;
    if (e < NE) {
      int s = esrc[e];
      int d = edst[e];
      int slot = atomicAdd(&lbase[s >> SSHIFT], 1);
      part1[slot] = make_int2(s, d);
    }
  }
}

// Pass 2: partition part1 by dst-bucket -> part2 (dst-bucket-major, src-ascending-ish)
__global__ __launch_bounds__(256) void k_partition2(
    const int2* __restrict__ part1, int* __restrict__ dcur, int2* __restrict__ part2) {
  __shared__ int lcnt[NBUK];
  __shared__ int lbase[NBUK];
  int tid = threadIdx.x;
  int e0 = blockIdx.x * EPB;
  for (int i = tid; i < NBUK; i += 256) lcnt[i] = 0;
  __syncthreads();
#pragma unroll
  for (int i = 0; i < EPB / 256; ++i) {
    int e = e0 + i * 256 + tid;
    if (e < NE) atomicAdd(&lcnt[part1[e].y >> DSHIFT], 1);
  }
  __syncthreads();
  for (int i = tid; i < NBUK; i += 256) {
    int c = lcnt[i];
    lbase[i] = c ? atomicAdd(&dcur[i], c) : 0;
  }
  __syncthreads();
#pragma unroll
  for (int i = 0; i < EPB / 256; ++i) {
    int e = e0 + i * 256 + tid;
    if (e < NE) {
      int2 p = part1[e];
      int slot = atomicAdd(&lbase[p.y >> DSHIFT], 1);
      part2[slot] = p;
    }
  }
}

// Per dst-bucket exact counting sort: part2 segment -> csr (src only, dst-major),
// emits offs[d] (absolute) and deg[d].
__global__ __launch_bounds__(256) void k_sort_dst(
    const int2* __restrict__ part2, const int* __restrict__ dboffs,
    int* __restrict__ offs, int* __restrict__ deg, int* __restrict__ csr) {
  __shared__ int lcnt[128];
  __shared__ int lof[128];
  __shared__ int lcur[128];
  int tid = threadIdx.x;
  int b = blockIdx.x;
  int d0 = b << DSHIFT;
  int ndst = ND - d0; if (ndst > 128) ndst = 128;
  int s0 = dboffs[b], s1 = dboffs[b + 1];
  if (tid < 128) lcnt[tid] = 0;
  __syncthreads();
  for (int e = s0 + tid; e < s1; e += 256) atomicAdd(&lcnt[part2[e].y - d0], 1);
  __syncthreads();
  if (tid < 128) lof[tid] = lcnt[tid];
  __syncthreads();
  for (int s = 1; s < 128; s <<= 1) {
    int a = (tid < 128 && tid >= s) ? lof[tid - s] : 0;
    __syncthreads();
    if (tid < 128) lof[tid] += a;
    __syncthreads();
  }
  if (tid < 128) {
    int ex = lof[tid] - lcnt[tid];
    lcur[tid] = ex;
    if (tid < ndst) {
      offs[d0 + tid] = s0 + ex;
      deg[d0 + tid] = lcnt[tid];
    }
  }
  __syncthreads();
  for (int e = s0 + tid; e < s1; e += 256) {
    int2 p = part2[e];
    int slot = s0 + atomicAdd(&lcur[p.y - d0], 1);
    csr[slot] = p.x;
  }
}

// One wave per dst node, edge loop unrolled x4 (round-5 structure, offs absolute).
__global__ __launch_bounds__(256) void k_agg(const int* __restrict__ csr, const int* __restrict__ offs,
    const int* __restrict__ deg, const float* __restrict__ el, const float* __restrict__ er,
    const uint32_t* __restrict__ h2, const float* __restrict__ bias, float* __restrict__ out) {
  int wid = (int)((blockIdx.x * blockDim.x + threadIdx.x) >> 6);
  int lane = threadIdx.x & 63;
  if (wid >= ND) return;
  int g = NS + wid;
  int hh = lane >> 3;
  float erv = er[(size_t)g * NH + hh];
  float w0 = el[(size_t)g * NH + hh] + erv;
  w0 = (w0 < 0.f) ? NEG * w0 : w0;
  w0 = __expf(w0);
  uint32_t hv = h2[(size_t)g * 64 + lane];
  float acc0 = w0 * __uint_as_float(hv << 16);
  float acc1 = w0 * __uint_as_float(hv & 0xffff0000u);
  float z = w0;
  int off = offs[wid], n = deg[wid];
  int t = 0;
  for (; t + 4 <= n; t += 4) {
    int s0 = csr[off + t], s1 = csr[off + t + 1], s2 = csr[off + t + 2], s3 = csr[off + t + 3];
    float e0 = el[(size_t)s0 * NH + hh];
    float e1 = el[(size_t)s1 * NH + hh];
    float e2 = el[(size_t)s2 * NH + hh];
    float e3 = el[(size_t)s3 * NH + hh];
    uint32_t b0 = h2[(size_t)s0 * 64 + lane];
    uint32_t b1 = h2[(size_t)s1 * 64 + lane];
    uint32_t b2 = h2[(size_t)s2 * 64 + lane];
    uint32_t b3 = h2[(size_t)s3 * 64 + lane];
    float w;
    w = e0 + erv; w = (w < 0.f) ? NEG * w : w; w = __expf(w);
    acc0 = fmaf(w, __uint_as_float(b0 << 16), acc0);
    acc1 = fmaf(w, __uint_as_float(b0 & 0xffff0000u), acc1); z += w;
    w = e1 + erv; w = (w < 0.f) ? NEG * w : w; w = __expf(w);
    acc0 = fmaf(w, __uint_as_float(b1 << 16), acc0);
    acc1 = fmaf(w, __uint_as_float(b1 & 0xffff0000u), acc1); z += w;
    w = e2 + erv; w = (w < 0.f) ? NEG * w : w; w = __expf(w);
    acc0 = fmaf(w, __uint_as_float(b2 << 16), acc0);
    acc1 = fmaf(w, __uint_as_float(b2 & 0xffff0000u), acc1); z += w;
    w = e3 + erv; w = (w < 0.f) ? NEG * w : w; w = __expf(w);
    acc0 = fmaf(w, __uint_as_float(b3 << 16), acc0);
    acc1 = fmaf(w, __uint_as_float(b3 & 0xffff0000u), acc1); z += w;
  }
  for (; t < n; ++t) {
    int src = csr[off + t];
    float wv = el[(size_t)src * NH + hh] + erv;
    wv = (wv < 0.f) ? NEG * wv : wv;
    wv = __expf(wv);
    uint32_t hb = h2[(size_t)src * 64 + lane];
    acc0 = fmaf(wv, __uint_as_float(hb << 16), acc0);
    acc1 = fmaf(wv, __uint_as_float(hb & 0xffff0000u), acc1);
    z += wv;
  }
  float inv = 1.f / z;
  int c = lane << 1;
  float2 o = make_float2(acc0 * inv + bias[c], acc1 * inv + bias[c + 1]);
  *(float2*)&out[(size_t)wid * HD + c] = o;
}

extern "C" void kernel_launch(void* const* d_in, const int* in_sizes, int n_in,
                              void* d_out, int out_size, void* d_ws, size_t ws_size,
                              hipStream_t stream) {
  const float* fs   = (const float*)d_in[0];
  const float* fd   = (const float*)d_in[1];
  const float* W    = (const float*)d_in[2];
  const float* al   = (const float*)d_in[3];
  const float* ar   = (const float*)d_in[4];
  const float* bias = (const float*)d_in[5];
  const int* esrc   = (const int*)d_in[6];
  const int* edst   = (const int*)d_in[7];
  float* out = (float*)d_out;
  (void)in_sizes; (void)n_in; (void)out_size; (void)ws_size;

  char* ws = (char*)d_ws;
  size_t o = 0;
  auto alloc = [&](size_t b) { size_t r = o; o += (b + 255) & ~(size_t)255; return r; };
  float*  Waug   = (float*)(ws + alloc((size_t)DINK * NAUG * 4));
  __hip_bfloat16* hbf = (__hip_bfloat16*)(ws + alloc((size_t)NTOT * HD * 2));
  float*  el     = (float*)(ws + alloc((size_t)NTOT * NH * 4));
  float*  er     = (float*)(ws + alloc((size_t)NTOT * NH * 4));
  int*    sbh    = (int*)(ws + alloc((size_t)NBUK * 4));
  int*    sboffs = (int*)(ws + alloc((size_t)NBUK * 4));
  int*    scur   = (int*)(ws + alloc((size_t)NBUK * 4));
  int*    dbh    = (int*)(ws + alloc((size_t)NBUK * 4));
  int*    dboffs = (int*)(ws + alloc((size_t)(NBUK + 1) * 4));
  int*    dcur   = (int*)(ws + alloc((size_t)NBUK * 4));
  int*    offs   = (int*)(ws + alloc((size_t)ND * 4));
  int*    deg    = (int*)(ws + alloc((size_t)ND * 4));
  int*    csr    = (int*)(ws + alloc((size_t)NE * 4));
  int2*   part1  = (int2*)(ws + alloc((size_t)NE * 8));
  int2*   part2  = (int2*)(ws + alloc((size_t)NE * 8));

  hipMemsetAsync(sbh, 0, (size_t)NBUK * 4, stream);
  hipMemsetAsync(dbh, 0, (size_t)NBUK * 4, stream);
  k_build_waug<<<(DINK * NAUG + 255) / 256, 256, 0, stream>>>(W, al, ar, Waug);
  k_hist2<<<256, 256, 0, stream>>>(esrc, edst, sbh, dbh);
  k_gemm_mfma<<<(NTOT + 63) / 64, 256, 0, stream>>>(fs, fd, Waug, hbf, el, er);
  k_scan_buckets<<<1, NBUK, 0, stream>>>(sbh, sboffs, scur);
  k_scan_buckets<<<1, NBUK, 0, stream>>>(dbh, dboffs, dcur);
  k_partition1<<<NPB, 256, 0, stream>>>(esrc, edst, scur, part1);
  k_partition2<<<NPB, 256, 0, stream>>>(part1, dcur, part2);
  k_sort_dst<<<NDB, 256, 0, stream>>>(part2, dboffs, offs, deg, csr);
  k_agg<<<ND / 4, 256, 0, stream>>>(csr, offs, deg, el, er, (const uint32_t*)hbf, bias, out);
}

// Round 12
// 457.740 us; speedup vs baseline: 4.0679x; 1.0029x over previous
//
#include <hip/hip_runtime.h>
#include <hip/hip_bf16.h>
#include <stdint.h>

#define NS   200000
#define ND   100000
#define NTOT 300000
#define NE   1600000
#define DINK 128
#define NH   8
#define DH   16
#define HD   128
#define NAUG 144
#define NEG  0.2f

#define NBUK   1024
#define SSHIFT 8
#define DSHIFT 7
#define EPB    8192
#define NPB    196
#define NDB    782

typedef __attribute__((ext_vector_type(8))) short short8;
typedef __attribute__((ext_vector_type(4))) float f32x4;

__device__ inline uint32_t bf16rne(uint32_t u) {
  return (u + 0x7fffu + ((u >> 16) & 1u)) >> 16;
}
__device__ inline uint32_t pack_bf2(float a, float b) {
  union { float f; uint32_t u; } ua, ub; ua.f = a; ub.f = b;
  return (bf16rne(ua.u) & 0xffffu) | (bf16rne(ub.u) << 16);
}

// Build W^T in bf16, already in the GEMM's swizzled LDS byte layout.
// Slot (n, s, lg) holds bf16 Waug[k][n] for k = s*32+lg*8+j, j=0..7, at
// byte (n*256 + s*64 + lg*16) ^ ((n&7)<<4).  2304 uint4 = 36 KB.
__global__ void k_build_wsw(const float* __restrict__ W, const float* __restrict__ al,
                            const float* __restrict__ ar, uint4* __restrict__ wsw) {
  int idx = blockIdx.x * 256 + threadIdx.x;
  if (idx >= NAUG * 16) return;
  int n = idx >> 4, rem = idx & 15;
  int s = rem >> 2, lg = rem & 3;
  int k0 = s * 32 + lg * 8;
  float v[8];
#pragma unroll
  for (int j = 0; j < 8; ++j) {
    int k = k0 + j;
    if (n < HD) {
      v[j] = W[k * HD + n];
    } else {
      int hh = (n - HD) & 7;
      const float* a = (n < HD + NH) ? al : ar;
      float sacc = 0.f;
      for (int d = 0; d < DH; ++d) sacc += W[k * HD + hh * DH + d] * a[hh * DH + d];
      v[j] = sacc;
    }
  }
  uint4 p;
  p.x = pack_bf2(v[0], v[1]); p.y = pack_bf2(v[2], v[3]);
  p.z = pack_bf2(v[4], v[5]); p.w = pack_bf2(v[6], v[7]);
  uint32_t byte = ((uint32_t)(n * 256 + s * 64 + lg * 16)) ^ ((uint32_t)(n & 7) << 4);
  *(uint4*)((char*)wsw + byte) = p;
}

// MFMA bf16 GEMM: BM=128, 512 threads (8 waves x 16 rows). W-stage = linear
// 16B copy of pre-swizzled wsw; A-stage = f32->bf16 pack into swizzled LDS.
__global__ __launch_bounds__(512) void k_gemm_mfma(
    const float* __restrict__ fs, const float* __restrict__ fd,
    const uint4* __restrict__ wsw, __hip_bfloat16* __restrict__ hbf,
    float* __restrict__ el, float* __restrict__ er) {
  __shared__ short lds_w[NAUG * DINK];   // 36 KB
  __shared__ short lds_a[128 * DINK];    // 32 KB
  int tid = threadIdx.x;
  int m0 = blockIdx.x * 128;

  for (int idx = tid; idx < NAUG * 16; idx += 512)
    ((uint4*)lds_w)[idx] = wsw[idx];

  {
    int row = tid >> 2, q = tid & 3;
    int grow = m0 + row;
    bool valid = grow < NTOT;
    const float* base = valid ? ((grow < NS) ? (fs + (size_t)grow * DINK)
                                             : (fd + (size_t)(grow - NS) * DINK)) : (const float*)0;
#pragma unroll
    for (int c = 0; c < 4; ++c) {
      int col = q * 32 + c * 8;
      float4 v0 = valid ? *(const float4*)(base + col)     : make_float4(0,0,0,0);
      float4 v1 = valid ? *(const float4*)(base + col + 4) : make_float4(0,0,0,0);
      uint4 p;
      p.x = pack_bf2(v0.x, v0.y); p.y = pack_bf2(v0.z, v0.w);
      p.z = pack_bf2(v1.x, v1.y); p.w = pack_bf2(v1.z, v1.w);
      uint32_t off = ((uint32_t)(row * DINK + col) * 2u) ^ ((uint32_t)(row & 7) << 4);
      *(uint4*)((char*)lds_a + off) = p;
    }
  }
  __syncthreads();

  int w = tid >> 6, lane = tid & 63;
  int lr = lane & 15, lg = lane >> 4;
  short8 af[4];
#pragma unroll
  for (int s = 0; s < 4; ++s) {
    uint32_t off = ((uint32_t)((w * 16 + lr) * DINK + s * 32 + lg * 8) * 2u)
                 ^ ((uint32_t)(lr & 7) << 4);
    af[s] = *(short8*)((char*)lds_a + off);
  }
  int orow0 = m0 + w * 16 + lg * 4;
#pragma unroll
  for (int t = 0; t < 9; ++t) {
    f32x4 acc = {0.f, 0.f, 0.f, 0.f};
#pragma unroll
    for (int s = 0; s < 4; ++s) {
      uint32_t off = ((uint32_t)((t * 16 + lr) * DINK + s * 32 + lg * 8) * 2u)
                   ^ ((uint32_t)(lr & 7) << 4);
      short8 bfr = *(short8*)((char*)lds_w + off);
      acc = __builtin_amdgcn_mfma_f32_16x16x32_bf16(af[s], bfr, acc, 0, 0, 0);
    }
#pragma unroll
    for (int j = 0; j < 4; ++j) {
      int row = orow0 + j;
      if (row >= NTOT) continue;
      float v = acc[j];
      if (t < 8)          hbf[(size_t)row * HD + t * 16 + lr] = __float2bfloat16(v);
      else if (lr < 8)    el[(size_t)row * NH + lr] = v;
      else                er[(size_t)row * NH + (lr - 8)] = v;
    }
  }
}

// One pass: src-bucket + dst-bucket histograms (both LDS-binned)
__global__ __launch_bounds__(256) void k_hist2(
    const int* __restrict__ esrc, const int* __restrict__ edst,
    int* __restrict__ sbh, int* __restrict__ dbh) {
  __shared__ int ls[NBUK];
  __shared__ int ld[NBUK];
  int tid = threadIdx.x;
  for (int i = tid; i < NBUK; i += 256) { ls[i] = 0; ld[i] = 0; }
  __syncthreads();
  for (int e = blockIdx.x * 256 + tid; e < NE; e += gridDim.x * 256) {
    atomicAdd(&ls[esrc[e] >> SSHIFT], 1);
    atomicAdd(&ld[edst[e] >> DSHIFT], 1);
  }
  __syncthreads();
  for (int i = tid; i < NBUK; i += 256) {
    if (ls[i]) atomicAdd(&sbh[i], ls[i]);
    if (ld[i]) atomicAdd(&dbh[i], ld[i]);
  }
}

// Exclusive scan of 1024 bucket counts -> offs and cur
__global__ void k_scan_buckets(const int* __restrict__ bh, int* __restrict__ offs,
                               int* __restrict__ cur) {
  __shared__ int sd[NBUK];
  int t = threadIdx.x;
  int v = bh[t];
  sd[t] = v;
  __syncthreads();
  for (int s = 1; s < NBUK; s <<= 1) {
    int a = (t >= s) ? sd[t - s] : 0;
    __syncthreads();
    sd[t] += a;
    __syncthreads();
  }
  int ex = sd[t] - v;
  offs[t] = ex;
  cur[t] = ex;
}

// Pass 1: partition raw edges by src-bucket -> part1 (src-bucket-major)
__global__ __launch_bounds__(256) void k_partition1(
    const int* __restrict__ esrc, const int* __restrict__ edst,
    int* __restrict__ scur, int2* __restrict__ part1) {
  __shared__ int lcnt[NBUK];
  __shared__ int lbase[NBUK];
  int tid = threadIdx.x;
  int e0 = blockIdx.x * EPB;
  for (int i = tid; i < NBUK; i += 256) lcnt[i] = 0;
  __syncthreads();
#pragma unroll
  for (int i = 0; i < EPB / 256; ++i) {
    int e = e0 + i * 256 + tid;
    if (e < NE) atomicAdd(&lcnt[esrc[e] >> SSHIFT], 1);
  }
  __syncthreads();
  for (int i = tid; i < NBUK; i += 256) {
    int c = lcnt[i];
    lbase[i] = c ? atomicAdd(&scur[i], c) : 0;
  }
  __syncthreads();
#pragma unroll
  for (int i = 0; i < EPB / 256; ++i) {
    int e = e0 + i * 256 + tid;
    if (e < NE) {
      int s = esrc[e];
      int d = edst[e];
      int slot = atomicAdd(&lbase[s >> SSHIFT], 1);
      part1[slot] = make_int2(s, d);
    }
  }
}

// Pass 2: partition part1 by dst-bucket -> part2 (dst-bucket-major, src-ascending-ish)
__global__ __launch_bounds__(256) void k_partition2(
    const int2* __restrict__ part1, int* __restrict__ dcur, int2* __restrict__ part2) {
  __shared__ int lcnt[NBUK];
  __shared__ int lbase[NBUK];
  int tid = threadIdx.x;
  int e0 = blockIdx.x * EPB;
  for (int i = tid; i < NBUK; i += 256) lcnt[i] = 0;
  __syncthreads();
#pragma unroll
  for (int i = 0; i < EPB / 256; ++i) {
    int e = e0 + i * 256 + tid;
    if (e < NE) atomicAdd(&lcnt[part1[e].y >> DSHIFT], 1);
  }
  __syncthreads();
  for (int i = tid; i < NBUK; i += 256) {
    int c = lcnt[i];
    lbase[i] = c ? atomicAdd(&dcur[i], c) : 0;
  }
  __syncthreads();
#pragma unroll
  for (int i = 0; i < EPB / 256; ++i) {
    int e = e0 + i * 256 + tid;
    if (e < NE) {
      int2 p = part1[e];
      int slot = atomicAdd(&lbase[p.y >> DSHIFT], 1);
      part2[slot] = p;
    }
  }
}

// Per dst-bucket exact counting sort: part2 segment -> csr, offs, deg.
__global__ __launch_bounds__(256) void k_sort_dst(
    const int2* __restrict__ part2, const int* __restrict__ dboffs,
    int* __restrict__ offs, int* __restrict__ deg, int* __restrict__ csr) {
  __shared__ int lcnt[128];
  __shared__ int lof[128];
  __shared__ int lcur[128];
  int tid = threadIdx.x;
  int b = blockIdx.x;
  int d0 = b << DSHIFT;
  int ndst = ND - d0; if (ndst > 128) ndst = 128;
  int s0 = dboffs[b], s1 = dboffs[b + 1];
  if (tid < 128) lcnt[tid] = 0;
  __syncthreads();
  for (int e = s0 + tid; e < s1; e += 256) atomicAdd(&lcnt[part2[e].y - d0], 1);
  __syncthreads();
  if (tid < 128) lof[tid] = lcnt[tid];
  __syncthreads();
  for (int s = 1; s < 128; s <<= 1) {
    int a = (tid < 128 && tid >= s) ? lof[tid - s] : 0;
    __syncthreads();
    if (tid < 128) lof[tid] += a;
    __syncthreads();
  }
  if (tid < 128) {
    int ex = lof[tid] - lcnt[tid];
    lcur[tid] = ex;
    if (tid < ndst) {
      offs[d0 + tid] = s0 + ex;
      deg[d0 + tid] = lcnt[tid];
    }
  }
  __syncthreads();
  for (int e = s0 + tid; e < s1; e += 256) {
    int2 p = part2[e];
    int slot = s0 + atomicAdd(&lcur[p.y - d0], 1);
    csr[slot] = p.x;
  }
}

// One wave per dst node, edge loop unrolled x4.
__global__ __launch_bounds__(256) void k_agg(const int* __restrict__ csr, const int* __restrict__ offs,
    const int* __restrict__ deg, const float* __restrict__ el, const float* __restrict__ er,
    const uint32_t* __restrict__ h2, const float* __restrict__ bias, float* __restrict__ out) {
  int wid = (int)((blockIdx.x * blockDim.x + threadIdx.x) >> 6);
  int lane = threadIdx.x & 63;
  if (wid >= ND) return;
  int g = NS + wid;
  int hh = lane >> 3;
  float erv = er[(size_t)g * NH + hh];
  float w0 = el[(size_t)g * NH + hh] + erv;
  w0 = (w0 < 0.f) ? NEG * w0 : w0;
  w0 = __expf(w0);
  uint32_t hv = h2[(size_t)g * 64 + lane];
  float acc0 = w0 * __uint_as_float(hv << 16);
  float acc1 = w0 * __uint_as_float(hv & 0xffff0000u);
  float z = w0;
  int off = offs[wid], n = deg[wid];
  int t = 0;
  for (; t + 4 <= n; t += 4) {
    int s0 = csr[off + t], s1 = csr[off + t + 1], s2 = csr[off + t + 2], s3 = csr[off + t + 3];
    float e0 = el[(size_t)s0 * NH + hh];
    float e1 = el[(size_t)s1 * NH + hh];
    float e2 = el[(size_t)s2 * NH + hh];
    float e3 = el[(size_t)s3 * NH + hh];
    uint32_t b0 = h2[(size_t)s0 * 64 + lane];
    uint32_t b1 = h2[(size_t)s1 * 64 + lane];
    uint32_t b2 = h2[(size_t)s2 * 64 + lane];
    uint32_t b3 = h2[(size_t)s3 * 64 + lane];
    float w;
    w = e0 + erv; w = (w < 0.f) ? NEG * w : w; w = __expf(w);
    acc0 = fmaf(w, __uint_as_float(b0 << 16), acc0);
    acc1 = fmaf(w, __uint_as_float(b0 & 0xffff0000u), acc1); z += w;
    w = e1 + erv; w = (w < 0.f) ? NEG * w : w; w = __expf(w);
    acc0 = fmaf(w, __uint_as_float(b1 << 16), acc0);
    acc1 = fmaf(w, __uint_as_float(b1 & 0xffff0000u), acc1); z += w;
    w = e2 + erv; w = (w < 0.f) ? NEG * w : w; w = __expf(w);
    acc0 = fmaf(w, __uint_as_float(b2 << 16), acc0);
    acc1 = fmaf(w, __uint_as_float(b2 & 0xffff0000u), acc1); z += w;
    w = e3 + erv; w = (w < 0.f) ? NEG * w : w; w = __expf(w);
    acc0 = fmaf(w, __uint_as_float(b3 << 16), acc0);
    acc1 = fmaf(w, __uint_as_float(b3 & 0xffff0000u), acc1); z += w;
  }
  for (; t < n; ++t) {
    int src = csr[off + t];
    float wv = el[(size_t)src * NH + hh] + erv;
    wv = (wv < 0.f) ? NEG * wv : wv;
    wv = __expf(wv);
    uint32_t hb = h2[(size_t)src * 64 + lane];
    acc0 = fmaf(wv, __uint_as_float(hb << 16), acc0);
    acc1 = fmaf(wv, __uint_as_float(hb & 0xffff0000u), acc1);
    z += wv;
  }
  float inv = 1.f / z;
  int c = lane << 1;
  float2 o = make_float2(acc0 * inv + bias[c], acc1 * inv + bias[c + 1]);
  *(float2*)&out[(size_t)wid * HD + c] = o;
}

extern "C" void kernel_launch(void* const* d_in, const int* in_sizes, int n_in,
                              void* d_out, int out_size, void* d_ws, size_t ws_size,
                              hipStream_t stream) {
  const float* fs   = (const float*)d_in[0];
  const float* fd   = (const float*)d_in[1];
  const float* W    = (const float*)d_in[2];
  const float* al   = (const float*)d_in[3];
  const float* ar   = (const float*)d_in[4];
  const float* bias = (const float*)d_in[5];
  const int* esrc   = (const int*)d_in[6];
  const int* edst   = (const int*)d_in[7];
  float* out = (float*)d_out;
  (void)in_sizes; (void)n_in; (void)out_size; (void)ws_size;

  char* ws = (char*)d_ws;
  size_t o = 0;
  auto alloc = [&](size_t b) { size_t r = o; o += (b + 255) & ~(size_t)255; return r; };
  uint4*  wsw    = (uint4*)(ws + alloc((size_t)NAUG * 16 * 16));
  __hip_bfloat16* hbf = (__hip_bfloat16*)(ws + alloc((size_t)NTOT * HD * 2));
  float*  el     = (float*)(ws + alloc((size_t)NTOT * NH * 4));
  float*  er     = (float*)(ws + alloc((size_t)NTOT * NH * 4));
  int*    sbh    = (int*)(ws + alloc((size_t)NBUK * 4));
  int*    sboffs = (int*)(ws + alloc((size_t)NBUK * 4));
  int*    scur   = (int*)(ws + alloc((size_t)NBUK * 4));
  int*    dbh    = (int*)(ws + alloc((size_t)NBUK * 4));
  int*    dboffs = (int*)(ws + alloc((size_t)(NBUK + 1) * 4));
  int*    dcur   = (int*)(ws + alloc((size_t)NBUK * 4));
  int*    offs   = (int*)(ws + alloc((size_t)ND * 4));
  int*    deg    = (int*)(ws + alloc((size_t)ND * 4));
  int*    csr    = (int*)(ws + alloc((size_t)NE * 4));
  int2*   part1  = (int2*)(ws + alloc((size_t)NE * 8));
  int2*   part2  = (int2*)(ws + alloc((size_t)NE * 8));

  hipMemsetAsync(sbh, 0, (size_t)NBUK * 4, stream);
  hipMemsetAsync(dbh, 0, (size_t)NBUK * 4, stream);
  k_build_wsw<<<(NAUG * 16 + 255) / 256, 256, 0, stream>>>(W, al, ar, wsw);
  k_hist2<<<256, 256, 0, stream>>>(esrc, edst, sbh, dbh);
  k_gemm_mfma<<<(NTOT + 127) / 128, 512, 0, stream>>>(fs, fd, wsw, hbf, el, er);
  k_scan_buckets<<<1, NBUK, 0, stream>>>(sbh, sboffs, scur);
  k_scan_buckets<<<1, NBUK, 0, stream>>>(dbh, dboffs, dcur);
  k_partition1<<<NPB, 256, 0, stream>>>(esrc, edst, scur, part1);
  k_partition2<<<NPB, 256, 0, stream>>>(part1, dcur, part2);
  k_sort_dst<<<NDB, 256, 0, stream>>>(part2, dboffs, offs, deg, csr);
  k_agg<<<ND / 4, 256, 0, stream>>>(csr, offs, deg, el, er, (const uint32_t*)hbf, bias, out);
}